// Round 5
// baseline (5131.536 us; speedup 1.0000x reference)
//
#include <hip/hip_runtime.h>
#include <math.h>

#define D_MODEL 2048
#define SQL 1024
#define SKVL 2560
#define HDIM 128

typedef __attribute__((ext_vector_type(8))) short bfrag;      // 8 bf16 as shorts (4 VGPR)
typedef __attribute__((ext_vector_type(4))) float f32x4;
typedef __attribute__((ext_vector_type(4))) unsigned short us4;

__device__ __forceinline__ unsigned short f2bf(float x) {
    unsigned int u = __float_as_uint(x);
    u += 0x7FFFu + ((u >> 16) & 1u);   // RNE
    return (unsigned short)(u >> 16);
}
__device__ __forceinline__ float bf2f(unsigned short h) {
    return __uint_as_float(((unsigned int)h) << 16);
}
__device__ __forceinline__ void split2(float x, unsigned short& h, unsigned short& l) {
    h = f2bf(x);
    l = f2bf(x - bf2f(h));
}
__device__ __forceinline__ void load16(const void* g, void* l) {
    __builtin_amdgcn_global_load_lds((const __attribute__((address_space(1))) unsigned int*)g,
                                     (__attribute__((address_space(3))) unsigned int*)l, 16, 0, 0);
}

// ---------------- RMSNorm -> split bf16 hi/lo ----------------
__global__ __launch_bounds__(256) void rms_kernel(
    const float* __restrict__ X, const float* __restrict__ w,
    unsigned short* __restrict__ H, unsigned short* __restrict__ L)
{
    int row = blockIdx.x;
    const float4* x4 = (const float4*)(X + (size_t)row * D_MODEL);
    const float4* w4 = (const float4*)w;
    __shared__ float red[256];
    float s = 0.f;
    for (int i = threadIdx.x; i < 512; i += 256) {
        float4 v = x4[i];
        s += v.x * v.x + v.y * v.y + v.z * v.z + v.w * v.w;
    }
    red[threadIdx.x] = s; __syncthreads();
    for (int st = 128; st > 0; st >>= 1) {
        if (threadIdx.x < st) red[threadIdx.x] += red[threadIdx.x + st];
        __syncthreads();
    }
    float r = rsqrtf(red[0] * (1.f / 2048.f) + 1e-6f);
    for (int i = threadIdx.x; i < 512; i += 256) {
        float4 v = x4[i], ww = w4[i];
        float y[4] = {v.x * r * ww.x, v.y * r * ww.y, v.z * r * ww.z, v.w * r * ww.w};
        us4 hh, ll;
#pragma unroll
        for (int j = 0; j < 4; ++j) { unsigned short a, b2; split2(y[j], a, b2); hh[j] = a; ll[j] = b2; }
        *(us4*)&H[(size_t)row * 2048 + i * 4] = hh;
        *(us4*)&L[(size_t)row * 2048 + i * 4] = ll;
    }
}

// ---------------- LayerNorm -> split bf16 hi/lo ----------------
__global__ __launch_bounds__(256) void ln_kernel(
    const float* __restrict__ X, const float* __restrict__ g, const float* __restrict__ b,
    unsigned short* __restrict__ H, unsigned short* __restrict__ L)
{
    int row = blockIdx.x;
    const float4* x4 = (const float4*)(X + (size_t)row * D_MODEL);
    __shared__ float red[256];
    float s = 0.f;
    for (int i = threadIdx.x; i < 512; i += 256) { float4 v = x4[i]; s += v.x + v.y + v.z + v.w; }
    red[threadIdx.x] = s; __syncthreads();
    for (int st = 128; st > 0; st >>= 1) {
        if (threadIdx.x < st) red[threadIdx.x] += red[threadIdx.x + st];
        __syncthreads();
    }
    float mu = red[0] * (1.f / 2048.f);
    __syncthreads();
    float vv = 0.f;
    for (int i = threadIdx.x; i < 512; i += 256) {
        float4 v = x4[i];
        float a0 = v.x - mu, a1 = v.y - mu, a2 = v.z - mu, a3 = v.w - mu;
        vv += a0 * a0 + a1 * a1 + a2 * a2 + a3 * a3;
    }
    red[threadIdx.x] = vv; __syncthreads();
    for (int st = 128; st > 0; st >>= 1) {
        if (threadIdx.x < st) red[threadIdx.x] += red[threadIdx.x + st];
        __syncthreads();
    }
    float rstd = rsqrtf(red[0] * (1.f / 2048.f) + 1e-5f);
    const float4* g4 = (const float4*)g;
    const float4* b4 = (const float4*)b;
    for (int i = threadIdx.x; i < 512; i += 256) {
        float4 v = x4[i], gg = g4[i], bb = b4[i];
        float y[4] = {(v.x - mu) * rstd * gg.x + bb.x, (v.y - mu) * rstd * gg.y + bb.y,
                      (v.z - mu) * rstd * gg.z + bb.z, (v.w - mu) * rstd * gg.w + bb.w};
        us4 hh, ll;
#pragma unroll
        for (int j = 0; j < 4; ++j) { unsigned short a, b2; split2(y[j], a, b2); hh[j] = a; ll[j] = b2; }
        *(us4*)&H[(size_t)row * 2048 + i * 4] = hh;
        *(us4*)&L[(size_t)row * 2048 + i * 4] = ll;
    }
}

// ---------------- elementwise fp32 -> bf16 hi/lo ----------------
__global__ __launch_bounds__(256) void csplit(
    const float* __restrict__ X, unsigned short* __restrict__ H, unsigned short* __restrict__ L, int n4)
{
    int i = blockIdx.x * 256 + threadIdx.x;
    if (i >= n4) return;
    float4 v = ((const float4*)X)[i];
    float y[4] = {v.x, v.y, v.z, v.w};
    us4 hh, ll;
#pragma unroll
    for (int j = 0; j < 4; ++j) { unsigned short a, b2; split2(y[j], a, b2); hh[j] = a; ll[j] = b2; }
    ((us4*)H)[i] = hh; ((us4*)L)[i] = ll;
}

// ------- transpose+split one column-chunk: W[K][N] cols [n0,n0+Nc) -> Th/Tl[Nc][K] -------
__global__ __launch_bounds__(256) void tsplit(
    const float* __restrict__ W, unsigned short* __restrict__ Th, unsigned short* __restrict__ Tl,
    int K, int N, int n0)
{
    __shared__ float tile[32][33];
    int bk = blockIdx.x * 32, bnl = blockIdx.y * 32;
    int t = threadIdx.x;
    int r = t >> 3, c4 = (t & 7) << 2;
    float4 v = *(const float4*)&W[(size_t)(bk + r) * N + n0 + bnl + c4];
    tile[r][c4 + 0] = v.x; tile[r][c4 + 1] = v.y; tile[r][c4 + 2] = v.z; tile[r][c4 + 3] = v.w;
    __syncthreads();
    us4 hh, ll;
#pragma unroll
    for (int j = 0; j < 4; ++j) {
        float x = tile[c4 + j][r];
        unsigned short a, b2; split2(x, a, b2);
        hh[j] = a; ll[j] = b2;
    }
    *(us4*)&Th[(size_t)(bnl + r) * K + bk + c4] = hh;
    *(us4*)&Tl[(size_t)(bnl + r) * K + bk + c4] = ll;
}

// ---------------- bf16x3 MFMA GEMM: C[:, nOff+...] = epi(A @ Bchunk^T) ----------------
// A: [M][K] bf16 hi/lo; B: [Nc][K] bf16 hi/lo (transposed weight chunk).
// 128x128 tile, BK=32, 4 waves (2x2), 4x4 fragments of 16x16x32 per wave.
// EPI: 0 = +bias, orow concat map; 1 = res + tg*(acc+bias); 2 = gelu -> split bf16; 3 = res + tg*acc
template <int EPI>
__global__ __launch_bounds__(256) void gemm_bf3(
    const unsigned short* __restrict__ Ah, const unsigned short* __restrict__ Al,
    const unsigned short* __restrict__ Bh, const unsigned short* __restrict__ Bl,
    const float* __restrict__ bias, float* __restrict__ Cf,
    unsigned short* __restrict__ Ch, unsigned short* __restrict__ Cl,
    int N, int K, int Sin, int Sout, int rowOff, int nOff,
    const float* __restrict__ res, const float* __restrict__ gate)
{
    __shared__ unsigned short As[2][4096];  // [hi/lo][128 rows x 32 k]
    __shared__ unsigned short Bs[2][4096];
    const int t = threadIdx.x;
    const int lane = t & 63;
    const int w = t >> 6, wr = w >> 1, wc = w & 1;
    const int fr = lane & 15, fq = lane >> 4;
    const int bm = blockIdx.y * 128, bn = blockIdx.x * 128;   // bn is chunk-local
    const int row0 = t >> 2, k80 = (t & 3) << 3;
    const int row1 = row0 + 64;

    f32x4 acc[4][4];
    f32x4 zz = {0.f, 0.f, 0.f, 0.f};
#pragma unroll
    for (int i = 0; i < 4; ++i)
#pragma unroll
        for (int j = 0; j < 4; ++j) acc[i][j] = zz;

    for (int kt = 0; kt < K; kt += 32) {
        load16(&Ah[(size_t)(bm + row0) * K + kt + k80], &As[0][(size_t)t * 8]);
        load16(&Ah[(size_t)(bm + row1) * K + kt + k80], &As[0][(size_t)(t + 256) * 8]);
        load16(&Al[(size_t)(bm + row0) * K + kt + k80], &As[1][(size_t)t * 8]);
        load16(&Al[(size_t)(bm + row1) * K + kt + k80], &As[1][(size_t)(t + 256) * 8]);
        load16(&Bh[(size_t)(bn + row0) * K + kt + k80], &Bs[0][(size_t)t * 8]);
        load16(&Bh[(size_t)(bn + row1) * K + kt + k80], &Bs[0][(size_t)(t + 256) * 8]);
        load16(&Bl[(size_t)(bn + row0) * K + kt + k80], &Bs[1][(size_t)t * 8]);
        load16(&Bl[(size_t)(bn + row1) * K + kt + k80], &Bs[1][(size_t)(t + 256) * 8]);
        __syncthreads();   // compiler drains vmcnt before s_barrier

        bfrag a_h[4], a_l[4], b_h[4], b_l[4];
#pragma unroll
        for (int i = 0; i < 4; ++i) {
            int ra = (wr * 64 + i * 16 + fr) * 32 + fq * 8;
            a_h[i] = *(const bfrag*)&As[0][ra];
            a_l[i] = *(const bfrag*)&As[1][ra];
            int rb = (wc * 64 + i * 16 + fr) * 32 + fq * 8;
            b_h[i] = *(const bfrag*)&Bs[0][rb];
            b_l[i] = *(const bfrag*)&Bs[1][rb];
        }
#pragma unroll
        for (int i = 0; i < 4; ++i)
#pragma unroll
            for (int j = 0; j < 4; ++j) {
                acc[i][j] = __builtin_amdgcn_mfma_f32_16x16x32_bf16(a_h[i], b_h[j], acc[i][j], 0, 0, 0);
                acc[i][j] = __builtin_amdgcn_mfma_f32_16x16x32_bf16(a_l[i], b_h[j], acc[i][j], 0, 0, 0);
                acc[i][j] = __builtin_amdgcn_mfma_f32_16x16x32_bf16(a_h[i], b_l[j], acc[i][j], 0, 0, 0);
            }
        __syncthreads();
    }

    float tg = 0.f;
    if (EPI == 1 || EPI == 3) tg = tanhf(gate[0]);
    float bj[4] = {0.f, 0.f, 0.f, 0.f};
    if (EPI == 0 || EPI == 1) {
#pragma unroll
        for (int j = 0; j < 4; ++j) bj[j] = bias[nOff + bn + wc * 64 + j * 16 + fr];
    }
#pragma unroll
    for (int i = 0; i < 4; ++i) {
#pragma unroll
        for (int r = 0; r < 4; ++r) {
            int m = bm + wr * 64 + i * 16 + fq * 4 + r;   // C/D: row=(lane>>4)*4+reg
            size_t orow = (EPI == 0) ? (size_t)((m / Sin) * Sout + rowOff + (m % Sin)) : (size_t)m;
#pragma unroll
            for (int j = 0; j < 4; ++j) {
                int gn = nOff + bn + wc * 64 + j * 16 + fr;   // C/D: col=lane&15
                float v = acc[i][j][r];
                if (EPI == 0) {
                    Cf[orow * N + gn] = v + bj[j];
                } else if (EPI == 1) {
                    v += bj[j];
                    Cf[orow * N + gn] = res[orow * N + gn] + tg * v;
                } else if (EPI == 2) {
                    v = 0.5f * v * (1.f + erff(v * 0.70710678f));
                    unsigned short a, b2; split2(v, a, b2);
                    Ch[orow * N + gn] = a; Cl[orow * N + gn] = b2;
                } else {
                    Cf[orow * N + gn] = res[orow * N + gn] + tg * v;
                }
            }
        }
    }
}

// ---------------- Flash attention (fp32) -> split bf16 ctx ----------------
__global__ __launch_bounds__(256) void attn_kernel(
    const float* __restrict__ Q, const float* __restrict__ K, const float* __restrict__ V,
    const float* __restrict__ mp, const float* __restrict__ ms, const float* __restrict__ mm,
    unsigned short* __restrict__ CH, unsigned short* __restrict__ CL)
{
    __shared__ float Qs[128][68];
    __shared__ float Ks[128][36];
    __shared__ float Vs[32][132];
    __shared__ float Ps[32][68];
    __shared__ float mk[32];
    const int t = threadIdx.x;
    const int b = blockIdx.y >> 4;
    const int h = blockIdx.y & 15;
    const int q0 = blockIdx.x * 64;
    {
        int qi = t & 63, d0 = t >> 6;
        const float* qp = Q + ((size_t)(b * SQL + q0 + qi)) * D_MODEL + h * HDIM;
#pragma unroll
        for (int i = 0; i < 32; ++i) {
            int d = d0 + (i << 2);
            Qs[d][qi] = qp[d] * 0.25f;   // scale = H^-0.5 = 0.25
        }
    }
    const int tq = t >> 4, tn = t & 15;
    float m_r[4], l_r[4], o_acc[4][8];
#pragma unroll
    for (int i = 0; i < 4; ++i) {
        m_r[i] = -1e30f; l_r[i] = 0.f;
#pragma unroll
        for (int d = 0; d < 8; ++d) o_acc[i][d] = 0.f;
    }
    __syncthreads();

    for (int kv0 = 0; kv0 < SKVL; kv0 += 32) {
        {
            int ki = t & 31, d0 = t >> 5;
            const float* kp = K + ((size_t)(b * SKVL + kv0 + ki)) * D_MODEL + h * HDIM;
#pragma unroll
            for (int i = 0; i < 16; ++i) {
                int d = d0 + (i << 3);
                Ks[d][ki] = kp[d];
            }
        }
#pragma unroll
        for (int i = 0; i < 4; ++i) {
            int f4 = t + (i << 8);
            int vi = f4 >> 5, d4 = (f4 & 31) << 2;
            *(float4*)&Vs[vi][d4] =
                *(const float4*)(V + ((size_t)(b * SKVL + kv0 + vi)) * D_MODEL + h * HDIM + d4);
        }
        if (t < 32) {
            int kvg = kv0 + t;
            float mv;
            if (kvg < 1024) mv = mp[b * 1024 + kvg];
            else if (kvg < 2048) mv = ms[b * 1024 + (kvg - 1024)];
            else mv = mm[b * 512 + (kvg - 2048)];
            mk[t] = mv;
        }
        __syncthreads();
        float s[4][2] = {};
        for (int d = 0; d < 128; ++d) {
            float4 qv = *(const float4*)&Qs[d][tq << 2];
            float2 kv2 = *(const float2*)&Ks[d][tn << 1];
            float qa[4] = {qv.x, qv.y, qv.z, qv.w};
#pragma unroll
            for (int i = 0; i < 4; ++i) {
                s[i][0] = fmaf(qa[i], kv2.x, s[i][0]);
                s[i][1] = fmaf(qa[i], kv2.y, s[i][1]);
            }
        }
        float mk0 = mk[tn << 1], mk1 = mk[(tn << 1) + 1];
        float alpha[4];
#pragma unroll
        for (int i = 0; i < 4; ++i) {
            float s0 = (mk0 == 0.f) ? -1e30f : s[i][0];
            float s1 = (mk1 == 0.f) ? -1e30f : s[i][1];
            float mx = fmaxf(s0, s1);
#pragma unroll
            for (int off = 1; off < 16; off <<= 1) mx = fmaxf(mx, __shfl_xor(mx, off, 64));
            float mnew = fmaxf(m_r[i], mx);
            alpha[i] = expf(m_r[i] - mnew);
            float p0 = expf(s0 - mnew), p1 = expf(s1 - mnew);
            float ps = p0 + p1;
#pragma unroll
            for (int off = 1; off < 16; off <<= 1) ps += __shfl_xor(ps, off, 64);
            m_r[i] = mnew;
            l_r[i] = l_r[i] * alpha[i] + ps;
            Ps[tn << 1][(tq << 2) + i] = p0;
            Ps[(tn << 1) + 1][(tq << 2) + i] = p1;
        }
        __syncthreads();
#pragma unroll
        for (int i = 0; i < 4; ++i)
#pragma unroll
            for (int dd = 0; dd < 8; ++dd) o_acc[i][dd] *= alpha[i];
        for (int kv = 0; kv < 32; ++kv) {
            float4 pv = *(const float4*)&Ps[kv][tq << 2];
            float4 va = *(const float4*)&Vs[kv][tn << 3];
            float4 vb = *(const float4*)&Vs[kv][(tn << 3) + 4];
            float pa[4] = {pv.x, pv.y, pv.z, pv.w};
            float vaa[4] = {va.x, va.y, va.z, va.w};
            float vbb[4] = {vb.x, vb.y, vb.z, vb.w};
#pragma unroll
            for (int i = 0; i < 4; ++i)
#pragma unroll
                for (int dd = 0; dd < 4; ++dd) {
                    o_acc[i][dd]     = fmaf(pa[i], vaa[dd], o_acc[i][dd]);
                    o_acc[i][dd + 4] = fmaf(pa[i], vbb[dd], o_acc[i][dd + 4]);
                }
        }
        __syncthreads();
    }
#pragma unroll
    for (int i = 0; i < 4; ++i) {
        float inv = 1.f / l_r[i];
        size_t bidx = ((size_t)(b * SQL + q0 + (tq << 2) + i)) * D_MODEL + h * HDIM + (tn << 3);
        us4 h0, l0, h1, l1;
#pragma unroll
        for (int dd = 0; dd < 4; ++dd) {
            unsigned short a, b2; split2(o_acc[i][dd] * inv, a, b2);
            h0[dd] = a; l0[dd] = b2;
        }
#pragma unroll
        for (int dd = 0; dd < 4; ++dd) {
            unsigned short a, b2; split2(o_acc[i][dd + 4] * inv, a, b2);
            h1[dd] = a; l1[dd] = b2;
        }
        *(us4*)&CH[bidx] = h0; *(us4*)&CH[bidx + 4] = h1;
        *(us4*)&CL[bidx] = l0; *(us4*)&CL[bidx + 4] = l1;
    }
}

extern "C" void kernel_launch(void* const* d_in, const int* in_sizes, int n_in,
                              void* d_out, int out_size, void* d_ws, size_t ws_size,
                              hipStream_t stream)
{
    (void)in_sizes; (void)n_in; (void)out_size; (void)ws_size;
    const float* qs   = (const float*)d_in[0];
    const float* pkv  = (const float*)d_in[1];
    const float* skvi = (const float*)d_in[2];
    const float* mkvi = (const float*)d_in[3];
    const float* mskp = (const float*)d_in[5];
    const float* msks = (const float*)d_in[6];
    const float* mskm = (const float*)d_in[7];
    const float* rmsw = (const float*)d_in[8];
    const float* Wq  = (const float*)d_in[9];  const float* bq  = (const float*)d_in[10];
    const float* Wkp = (const float*)d_in[11]; const float* bkp = (const float*)d_in[12];
    const float* Wvp = (const float*)d_in[13]; const float* bvp = (const float*)d_in[14];
    const float* Wks = (const float*)d_in[15]; const float* bks = (const float*)d_in[16];
    const float* Wvs = (const float*)d_in[17]; const float* bvs = (const float*)d_in[18];
    const float* Wkm = (const float*)d_in[19]; const float* bkm = (const float*)d_in[20];
    const float* Wvm = (const float*)d_in[21]; const float* bvm = (const float*)d_in[22];
    const float* Wo  = (const float*)d_in[23]; const float* bo  = (const float*)d_in[24];
    const float* lng = (const float*)d_in[25]; const float* lnb = (const float*)d_in[26];
    const float* W1  = (const float*)d_in[27]; const float* W2  = (const float*)d_in[28];
    const float* ga  = (const float*)d_in[29]; const float* gf  = (const float*)d_in[30];

    // -------- workspace layout: 131,072,000 B total (< 128 MiB known-safe) --------
    char* base = (char*)d_ws;
    unsigned short* pk_h = (unsigned short*)(base + 0);
    unsigned short* pk_l = (unsigned short*)(base + 5242880);
    unsigned short* sk_h = (unsigned short*)(base + 10485760);
    unsigned short* sk_l = (unsigned short*)(base + 14680064);
    unsigned short* mk_h = (unsigned short*)(base + 18874368);
    unsigned short* mk_l = (unsigned short*)(base + 20447232);
    unsigned short* wb_h = (unsigned short*)(base + 22020096);   // 4 MiB cycled weight buf (hi)
    unsigned short* wb_l = (unsigned short*)(base + 26214400);   // 4 MiB (lo)
    float* qb = (float*)(base + 30408704);                       // 16 MiB
    float* kb = (float*)(base + 47185920);                       // 40 MiB
    float* vb = (float*)(base + 89128960);                       // 40 MiB  (ends 131,072,000)
    // aliases (lifetimes verified):
    unsigned short* qn_h = (unsigned short*)kb;                  // rmsnorm out; dead before K-projs
    unsigned short* qn_l = (unsigned short*)((char*)kb + 8388608);
    unsigned short* ctx_h = pk_h;                                // attn out; pk/sk dead by then
    unsigned short* ctx_l = (unsigned short*)(base + 8388608);
    unsigned short* xln_h = pk_h;                                // ln out; ctx dead after Wo GEMM
    unsigned short* xln_l = (unsigned short*)(base + 8388608);
    float* hb = qb;                                              // residual h; qb dead after attn
    unsigned short* tb_h = (unsigned short*)kb;                  // FFN mid; kb/vb dead after attn
    unsigned short* tb_l = (unsigned short*)((char*)kb + 33554432);

    dim3 blk(256);

    // activations -> split bf16
    rms_kernel<<<2048, blk, 0, stream>>>(qs, rmsw, qn_h, qn_l);
    csplit<<<2560, blk, 0, stream>>>(pkv, pk_h, pk_l, 655360);
    csplit<<<2048, blk, 0, stream>>>(skvi, sk_h, sk_l, 524288);
    csplit<<<768,  blk, 0, stream>>>(mkvi, mk_h, mk_l, 196608);

    // chunked weight transpose+split -> GEMM, cycling wb_h/wb_l
    auto proj = [&](const unsigned short* Ah, const unsigned short* Al,
                    const float* W, const float* bias, float* out,
                    int M, int K, int Nc, int nchunks, int Sin, int Sout, int rowOff) {
        for (int c = 0; c < nchunks; ++c) {
            tsplit<<<dim3(K / 32, Nc / 32), blk, 0, stream>>>(W, wb_h, wb_l, K, 2048, c * Nc);
            gemm_bf3<0><<<dim3(Nc / 128, M / 128), blk, 0, stream>>>(
                Ah, Al, wb_h, wb_l, bias, out, nullptr, nullptr,
                2048, K, Sin, Sout, rowOff, c * Nc, nullptr, nullptr);
        }
    };

    proj(qn_h, qn_l, Wq,  bq,  qb, 2048, 2048, 1024, 2, 2048, 2048, 0);     // Q (before kb reused)
    proj(pk_h, pk_l, Wkp, bkp, kb, 2048, 1280, 1024, 2, 1024, 2560, 0);     // K protein
    proj(sk_h, sk_l, Wks, bks, kb, 2048, 1024, 2048, 1, 1024, 2560, 1024);  // K structure
    proj(mk_h, mk_l, Wkm, bkm, kb, 1024, 768,  2048, 1, 512,  2560, 2048);  // K msa
    proj(pk_h, pk_l, Wvp, bvp, vb, 2048, 1280, 1024, 2, 1024, 2560, 0);     // V protein
    proj(sk_h, sk_l, Wvs, bvs, vb, 2048, 1024, 2048, 1, 1024, 2560, 1024);  // V structure
    proj(mk_h, mk_l, Wvm, bvm, vb, 1024, 768,  2048, 1, 512,  2560, 2048);  // V msa

    attn_kernel<<<dim3(16, 32), blk, 0, stream>>>(qb, kb, vb, mskp, msks, mskm, ctx_h, ctx_l);

    // Wo GEMM: h = qs + tanh(ga)*(ctx@Wo + bo)   (2 chunks of 1024)
    for (int c = 0; c < 2; ++c) {
        tsplit<<<dim3(64, 32), blk, 0, stream>>>(Wo, wb_h, wb_l, 2048, 2048, c * 1024);
        gemm_bf3<1><<<dim3(8, 16), blk, 0, stream>>>(
            ctx_h, ctx_l, wb_h, wb_l, bo, hb, nullptr, nullptr,
            2048, 2048, 2048, 2048, 0, c * 1024, qs, ga);
    }

    ln_kernel<<<2048, blk, 0, stream>>>(hb, lng, lnb, xln_h, xln_l);

    // W1 GEMM: tb = gelu(xln@W1) -> split bf16   (8 chunks of 1024)
    for (int c = 0; c < 8; ++c) {
        tsplit<<<dim3(64, 32), blk, 0, stream>>>(W1, wb_h, wb_l, 2048, 8192, c * 1024);
        gemm_bf3<2><<<dim3(8, 16), blk, 0, stream>>>(
            xln_h, xln_l, wb_h, wb_l, nullptr, nullptr, tb_h, tb_l,
            8192, 2048, 2048, 2048, 0, c * 1024, nullptr, nullptr);
    }

    // W2 GEMM: out = hb + tanh(gf)*(tb@W2)   (8 chunks of 256)
    for (int c = 0; c < 8; ++c) {
        tsplit<<<dim3(256, 8), blk, 0, stream>>>(W2, wb_h, wb_l, 8192, 2048, c * 256);
        gemm_bf3<3><<<dim3(2, 16), blk, 0, stream>>>(
            tb_h, tb_l, wb_h, wb_l, nullptr, (float*)d_out, nullptr, nullptr,
            2048, 8192, 2048, 2048, 0, c * 256, hb, gf);
    }
}